// Round 23
// baseline (174.655 us; speedup 1.0000x reference)
//
#include <hip/hip_runtime.h>

typedef unsigned short u16;
typedef unsigned char u8;
typedef unsigned int u32;
typedef unsigned long long u64;

using s16x8 = __attribute__((ext_vector_type(8))) short;
using u16x4 = __attribute__((ext_vector_type(4))) u16;
using u32x2 = __attribute__((ext_vector_type(2))) u32;
using u32x4 = __attribute__((ext_vector_type(4))) u32;
using f32x4 = __attribute__((ext_vector_type(4))) float;

constexpr int N_ = 3072;
constexpr int E_ = 512;
constexpr int H_ = 8;
// exp(0.125*s) = exp2(s * 0.125*log2(e))
#define EXPSC 0.1803368801111203f

__device__ __forceinline__ u16 f2bf(float f) {
    u32 u = __float_as_uint(f);
    u += 0x7fffu + ((u >> 16) & 1u);
    return (u16)(u >> 16);
}
__device__ __forceinline__ float b2f(u16 u) {
    return __uint_as_float(((u32)u) << 16);
}
__device__ __forceinline__ u32 cvt_pk_bf16(float lo, float hi) {
    u32 r;
    asm("v_cvt_pk_bf16_f32 %0, %1, %2" : "=v"(r) : "v"(lo), "v"(hi));
    return r;
}

// ---------- K0: f32 -> bf16 convert ----------
__global__ void k_cvt(const float* __restrict__ src, u16* __restrict__ dst, int n4) {
    int i = blockIdx.x * blockDim.x + threadIdx.x;
    if (i >= n4) return;
    float4 v = ((const float4*)src)[i];
    u16x4 o = { f2bf(v.x), f2bf(v.y), f2bf(v.z), f2bf(v.w) };
    ((u16x4*)dst)[i] = o;
}

// ---------- K0b: pack adj int32 -> TRANSPOSED bitmask u64: adjpT[mword][n] ----------
__global__ void k_adjpack(const int* __restrict__ adj, u64* __restrict__ adjpT) {
    int i = blockIdx.x * blockDim.x + threadIdx.x;
    int v = adj[i];
    u64 m = __ballot(v != 0);
    if ((threadIdx.x & 63) == 0) {
        int n = i / 3072;
        int mw = (i - n * 3072) >> 6;
        adjpT[mw * 3072 + n] = m;
    }
}

// ---------- K1: projection GEMM (proven) ----------
__global__ __launch_bounds__(256) void k_proj(
    const u16* __restrict__ xb, const u16* __restrict__ wqb,
    const u16* __restrict__ wkb, u16* __restrict__ Qb, u16* __restrict__ Kb)
{
    const int t = threadIdx.x, lane = t & 63, w = t >> 6;
    const int lr = lane & 15, lg = lane >> 4;
    const int n0 = blockIdx.x * 64 + w * 16;
    const int e0 = blockIdx.y * 64;
    const u16* wb = blockIdx.z ? wkb : wqb;
    u16* dst = blockIdx.z ? Kb : Qb;

    f32x4 acc[4];
#pragma unroll
    for (int cb = 0; cb < 4; ++cb) acc[cb] = f32x4{0.f, 0.f, 0.f, 0.f};

    for (int k0 = 0; k0 < 512; k0 += 32) {
        s16x8 a = *(const s16x8*)(xb + (n0 + lr) * 512 + k0 + lg * 8);
#pragma unroll
        for (int cb = 0; cb < 4; ++cb) {
            s16x8 b = *(const s16x8*)(wb + (e0 + cb * 16 + lr) * 512 + k0 + lg * 8);
            acc[cb] = __builtin_amdgcn_mfma_f32_16x16x32_bf16(a, b, acc[cb], 0, 0, 0);
        }
    }
#pragma unroll
    for (int cb = 0; cb < 4; ++cb)
#pragma unroll
        for (int r = 0; r < 4; ++r)
            dst[(n0 + lg * 4 + r) * 512 + e0 + cb * 16 + lr] = f2bf(acc[cb][r]);
}

// ---------- K2t: transpose Kb -> Kt[512][3072] (proven) ----------
__global__ __launch_bounds__(256) void k_transpose(const u16* __restrict__ Kb,
                                                   u16* __restrict__ Kt) {
    __shared__ u16 tile[64 * 68];
    const int t = threadIdx.x;
    const int n0 = blockIdx.x * 64, e0 = blockIdx.y * 64;
    const int tr = t >> 4, c4 = (t & 15) * 4;
#pragma unroll
    for (int p = 0; p < 4; ++p) {
        int row = p * 16 + tr;
        u16x4 v = *(const u16x4*)(Kb + (n0 + row) * 512 + e0 + c4);
        *(u16x4*)&tile[row * 68 + c4] = v;
    }
    __syncthreads();
#pragma unroll
    for (int p = 0; p < 4; ++p) {
        int er = p * 16 + tr;
        u16x4 v = { tile[(c4 + 0) * 68 + er], tile[(c4 + 1) * 68 + er],
                    tile[(c4 + 2) * 68 + er], tile[(c4 + 3) * 68 + er] };
        *(u16x4*)(Kt + (e0 + er) * 3072 + n0 + c4) = v;
    }
}

// ---------- K2f: repack Kb into QK B-fragment-major layout (proven r11) ----------
__global__ __launch_bounds__(256) void k_repack_qk(const u16* __restrict__ Kb,
                                                   u16* __restrict__ Kf) {
    const int gid = blockIdx.x * 256 + threadIdx.x;
    const int frag = gid >> 6, lane = gid & 63;
    const int lr = lane & 15, lg = lane >> 4;
    const int M16 = frag >> 4, h = (frag >> 1) & 7, ks = frag & 1;
    s16x8 v = *(const s16x8*)(Kb + (M16 * 16 + lr) * 512 + h * 64 + ks * 32 + lg * 8);
    *(s16x8*)(Kf + frag * 512 + lane * 8) = v;
}

// ---------- K2g: repack Kt into PV B-fragment-major layout (proven r11) ----------
__global__ __launch_bounds__(256) void k_repack_pv(const u16* __restrict__ Kt,
                                                   u16* __restrict__ Ktf) {
    const int gid = blockIdx.x * 256 + threadIdx.x;
    const int frag = gid >> 6, lane = gid & 63;
    const int lr = lane & 15, lg = lane >> 4;
    const int h = frag / 384;
    const int rem = frag - h * 384;
    const int db = rem / 96, M32 = rem - db * 96;
    s16x8 v = *(const s16x8*)(Kt + (h * 64 + db * 16 + lr) * 3072 + M32 * 32 + lg * 8);
    *(s16x8*)(Ktf + frag * 512 + lane * 8) = v;
}

// ---------- K3: pass 1 — wave = head, n-tile 32 (2 ns); 24 m-chunks of 128.
__global__ __launch_bounds__(512, 4) void k_pass1(
    const u16* __restrict__ Qb, const u16* __restrict__ Kf,
    const u64* __restrict__ adjpT, float* __restrict__ sep)
{
    const int t = threadIdx.x, lane = t & 63, h = t >> 6;
    const int lr = lane & 15, lg = lane >> 4;
    const int n0 = blockIdx.x * 32;
    const int mbase = blockIdx.y * 128;

    s16x8 qa[2][2];   // [ns][ks]
#pragma unroll
    for (int ns = 0; ns < 2; ++ns)
#pragma unroll
        for (int ks = 0; ks < 2; ++ks)
            qa[ns][ks] = *(const s16x8*)(Qb + (n0 + ns * 16 + lr) * 512 +
                                         h * 64 + ks * 32 + lg * 8);
    float racc[2][4];
#pragma unroll
    for (int ns = 0; ns < 2; ++ns)
#pragma unroll
        for (int cb = 0; cb < 4; ++cb) racc[ns][cb] = 0.f;
    const f32x4 z = {0.f, 0.f, 0.f, 0.f};

    for (int ms = 0; ms < 2; ++ms) {
        const int m0 = mbase + ms * 64;
        const u64 aw0 = adjpT[(m0 >> 6) * 3072 + n0 + lr];
        const u64 aw1 = adjpT[(m0 >> 6) * 3072 + n0 + 16 + lr];
        s16x8 kf[4][2];
#pragma unroll
        for (int cb = 0; cb < 4; ++cb) {
            const u16* fb = Kf + (((m0 >> 4) + cb) * 16 + h * 2) * 512 + lane * 8;
            kf[cb][0] = *(const s16x8*)(fb);
            kf[cb][1] = *(const s16x8*)(fb + 512);
        }
#pragma unroll
        for (int cb = 0; cb < 4; ++cb) {
#pragma unroll
            for (int ns = 0; ns < 2; ++ns) {
                f32x4 s = __builtin_amdgcn_mfma_f32_16x16x32_bf16(kf[cb][0], qa[ns][0], z, 0, 0, 0);
                s = __builtin_amdgcn_mfma_f32_16x16x32_bf16(kf[cb][1], qa[ns][1], s, 0, 0, 0);
                const u64 aw = ns ? aw1 : aw0;
                const u32 nib = (u32)(aw >> (cb * 16 + lg * 4)) & 0xFu;
                float e0 = (nib & 1u) ? exp2f(EXPSC * s[0]) : 0.f;
                float e1 = (nib & 2u) ? exp2f(EXPSC * s[1]) : 0.f;
                float e2 = (nib & 4u) ? exp2f(EXPSC * s[2]) : 0.f;
                float e3 = (nib & 8u) ? exp2f(EXPSC * s[3]) : 0.f;
                racc[ns][cb] += (e0 + e1) + (e2 + e3);
            }
        }
    }
#pragma unroll
    for (int ns = 0; ns < 2; ++ns) {
        float v = (racc[ns][0] + racc[ns][1]) + (racc[ns][2] + racc[ns][3]);
        v += __shfl_xor(v, 16);
        v += __shfl_xor(v, 32);
        if (lane < 16)
            sep[(blockIdx.y * 8 + h) * N_ + n0 + ns * 16 + lr] = v;
    }
}

// ---------- K4: finish — inv_se + energies (24 partials) ----------
__global__ __launch_bounds__(64) void k_finish(
    const u16* __restrict__ Qb, const float* __restrict__ sep,
    float* __restrict__ inv_se, float* __restrict__ energies)
{
    const int lane = threadIdx.x;
    const int r = lane >> 3;
    const int h = lane & 7;
    const int n = blockIdx.x * 8 + r;

    float se = 0.f;
#pragma unroll
    for (int c = 0; c < 24; ++c) se += sep[(c * 8 + h) * N_ + n];

    float q2 = 0.f;
    const u16* qrow = Qb + n * 512 + h * 64;
#pragma unroll
    for (int j = 0; j < 8; ++j) {
        s16x8 v = *(const s16x8*)(qrow + j * 8);
#pragma unroll
        for (int e = 0; e < 8; ++e) {
            float f = b2f((u16)v[e]);
            q2 += f * f;
        }
    }

    inv_se[h * N_ + n] = 1.f / se;
    energies[h * N_ + n] = -8.0f * logf(se) + 0.5f * q2;
}

// ---------- K5: pass 2 — wave = head, n-tile 32 (2 ns); kt reused across ns;
// packed-bf16 P in LDS (stride 19) for amean head-sum. (EXACT r20/r22, proven)
__global__ __launch_bounds__(512, 4) void k_pass2(
    const u16* __restrict__ Qb, const u16* __restrict__ Kf,
    const u16* __restrict__ Ktf, const float* __restrict__ inv_se,
    const u64* __restrict__ adjpT, float* __restrict__ amean,
    float* __restrict__ pout, int mrange)
{
    __shared__ u32 plds[8 * 64 * 19];   // [head][lane][2ns x 4cb x 2 u32, pad->19]
    const int t = threadIdx.x, lane = t & 63, h = t >> 6;   // wave = head
    const int lr = lane & 15, lg = lane >> 4;
    const int n0 = blockIdx.x * 32;
    const int mbase = blockIdx.y * mrange;

    s16x8 qa[2][2];   // [ns][ks]
#pragma unroll
    for (int ns = 0; ns < 2; ++ns)
#pragma unroll
        for (int ks = 0; ks < 2; ++ks)
            qa[ns][ks] = *(const s16x8*)(Qb + (n0 + ns * 16 + lr) * 512 +
                                         h * 64 + ks * 32 + lg * 8);
    float invv[2];
#pragma unroll
    for (int ns = 0; ns < 2; ++ns)
        invv[ns] = inv_se[h * N_ + n0 + ns * 16 + lr];

    f32x4 oacc[2][4];   // [ns][db]
#pragma unroll
    for (int ns = 0; ns < 2; ++ns)
#pragma unroll
        for (int db = 0; db < 4; ++db) oacc[ns][db] = f32x4{0.f, 0.f, 0.f, 0.f};

    // PV A-frag shuffle sources (verified r8-r18): lane lr holds P[n=..+lr].
    const int srcA = lr | (((lg * 2) & 3) << 4);
    const int srcB = lr | (((lg * 2 + 1) & 3) << 4);
    const bool hi = lg >= 2;

    const f32x4 z = {0.f, 0.f, 0.f, 0.f};
    const int msteps = mrange >> 6;
    for (int ms = 0; ms < msteps; ++ms) {
        const int m0 = mbase + ms * 64;
        const u64 aw0 = adjpT[(m0 >> 6) * 3072 + n0 + lr];
        const u64 aw1 = adjpT[(m0 >> 6) * 3072 + n0 + 16 + lr];
        // batched kf: 8 fragments for this (step, head)
        s16x8 kf[4][2];
#pragma unroll
        for (int cb = 0; cb < 4; ++cb) {
            const u16* fb = Kf + (((m0 >> 4) + cb) * 16 + h * 2) * 512 + lane * 8;
            kf[cb][0] = *(const s16x8*)(fb);
            kf[cb][1] = *(const s16x8*)(fb + 512);
        }
        // QK for both ns; P packed to registers + LDS
        u32 pw[2][4][2];   // [ns][cb][pair]
#pragma unroll
        for (int cb = 0; cb < 4; ++cb) {
#pragma unroll
            for (int ns = 0; ns < 2; ++ns) {
                f32x4 s = __builtin_amdgcn_mfma_f32_16x16x32_bf16(kf[cb][0], qa[ns][0], z, 0, 0, 0);
                s = __builtin_amdgcn_mfma_f32_16x16x32_bf16(kf[cb][1], qa[ns][1], s, 0, 0, 0);
                const u64 aw = ns ? aw1 : aw0;
                const u32 nib = (u32)(aw >> (cb * 16 + lg * 4)) & 0xFu;
                float p0 = (nib & 1u) ? exp2f(EXPSC * s[0]) * invv[ns] : 0.f;
                float p1 = (nib & 2u) ? exp2f(EXPSC * s[1]) * invv[ns] : 0.f;
                float p2 = (nib & 4u) ? exp2f(EXPSC * s[2]) * invv[ns] : 0.f;
                float p3 = (nib & 8u) ? exp2f(EXPSC * s[3]) * invv[ns] : 0.f;
                pw[ns][cb][0] = cvt_pk_bf16(p0, p1);
                pw[ns][cb][1] = cvt_pk_bf16(p2, p3);
                u32x2 pv = { pw[ns][cb][0], pw[ns][cb][1] };
                *(u32x2*)&plds[(h * 64 + lane) * 19 + ns * 8 + cb * 2] = pv;
            }
        }
        // PV: kt batched per ks, REUSED for both ns
#pragma unroll
        for (int ks = 0; ks < 2; ++ks) {
            s16x8 kt4[4];
#pragma unroll
            for (int db = 0; db < 4; ++db)
                kt4[db] = *(const s16x8*)(Ktf + ((h * 4 + db) * 96 +
                                          (m0 >> 5) + ks) * 512 + lane * 8);
#pragma unroll
            for (int ns = 0; ns < 2; ++ns) {
                u32 a0 = pw[ns][2 * ks][0], a1 = pw[ns][2 * ks][1];
                u32 c0 = pw[ns][2 * ks + 1][0], c1 = pw[ns][2 * ks + 1][1];
                u32 y00 = (u32)__shfl((int)a0, srcA);
                u32 y01 = (u32)__shfl((int)a1, srcA);
                u32 y02 = (u32)__shfl((int)a0, srcB);
                u32 y03 = (u32)__shfl((int)a1, srcB);
                u32 y10 = (u32)__shfl((int)c0, srcA);
                u32 y11 = (u32)__shfl((int)c1, srcA);
                u32 y12 = (u32)__shfl((int)c0, srcB);
                u32 y13 = (u32)__shfl((int)c1, srcB);
                u32x4 pav = { hi ? y10 : y00, hi ? y11 : y01,
                              hi ? y12 : y02, hi ? y13 : y03 };
                s16x8 pa = *(s16x8*)&pav;
#pragma unroll
                for (int db = 0; db < 4; ++db)
                    oacc[ns][db] = __builtin_amdgcn_mfma_f32_16x16x32_bf16(
                        pa, kt4[db], oacc[ns][db], 0, 0, 0);
            }
        }
        __syncthreads();
        {   // attn_mean: thread -> (row nl = t>>4 in [0,32), m-quad q = t&15);
            // one f32x4 quad per thread: 512 = 32 rows x 16 quads.
            const int nl = t >> 4;
            const int q = t & 15;
            const int srcl = (q & 3) * 16 + (nl & 15);
            const int idx = (nl >> 4) * 8 + (q >> 2) * 2;
            f32x4 sm = {0.f, 0.f, 0.f, 0.f};
#pragma unroll
            for (int wv = 0; wv < 8; ++wv) {
                u32x2 v = *(const u32x2*)&plds[(wv * 64 + srcl) * 19 + idx];
                sm[0] += b2f((u16)(v.x & 0xffffu));
                sm[1] += b2f((u16)(v.x >> 16));
                sm[2] += b2f((u16)(v.y & 0xffffu));
                sm[3] += b2f((u16)(v.y >> 16));
            }
            f32x4 o;
#pragma unroll
            for (int j = 0; j < 4; ++j) o[j] = sm[j] * 0.125f;
            *(f32x4*)(amean + (size_t)(n0 + nl) * 3072 + m0 + q * 4) = o;
        }
        __syncthreads();
    }
    float* po = pout + (size_t)blockIdx.y * (N_ * E_);
#pragma unroll
    for (int ns = 0; ns < 2; ++ns)
#pragma unroll
        for (int db = 0; db < 4; ++db)
#pragma unroll
            for (int r = 0; r < 4; ++r)
                po[(n0 + ns * 16 + lg * 4 + r) * 512 +
                   h * 64 + db * 16 + lr] = oacc[ns][db][r];
}

// ---------- K6: reduce partial out ----------
__global__ void k_reduce(const float* __restrict__ pout, float* __restrict__ out, int c2) {
    int i = blockIdx.x * blockDim.x + threadIdx.x;
    if (i >= (N_ * E_) / 4) return;
    const f32x4* p4 = (const f32x4*)pout;
    f32x4 s = p4[i];
    for (int c = 1; c < c2; ++c) s += p4[c * ((N_ * E_) / 4) + i];
    ((f32x4*)out)[i] = s;
}

extern "C" void kernel_launch(void* const* d_in, const int* in_sizes, int n_in,
                              void* d_out, int out_size, void* d_ws, size_t ws_size,
                              hipStream_t stream) {
    const float* x  = (const float*)d_in[0];
    const int*  adj = (const int*)d_in[1];     // bool input arrives as int32
    const float* WQ = (const float*)d_in[2];
    const float* WK = (const float*)d_in[3];
    float* out      = (float*)d_out;
    float* amean    = out + (size_t)N_ * E_;
    float* energies = out + (size_t)N_ * E_ + (size_t)N_ * N_;

    char* ws = (char*)d_ws;
    u16* xb     = (u16*)(ws);                 // dead after k_proj
    u64* adjpT  = (u64*)(ws);                 // aliases xb, written after k_proj
    u16* wqb    = (u16*)(ws + 3145728);
    u16* wkb    = (u16*)(ws + 3670016);
    u16* Qb     = (u16*)(ws + 4194304);
    u16* Kb     = (u16*)(ws + 7340032);
    u16* Kt     = (u16*)(ws + 10485760);
    u16* Kf     = (u16*)(ws + 13631488);      // 3 MB QK fragments
    u16* Ktf    = (u16*)(ws + 16777216);      // 3 MB PV fragments
    float* sep  = (float*)(ws + 19922944);    // 24 chunks x 8 heads x 3072 = 2.36 MB
    float* inv_se = (float*)(ws + 22282240);  // 96 KB
    float* pout = (float*)(ws + 22380544);

    int c2 = 1;
    const int cands[7] = {12, 8, 6, 4, 3, 2, 1};
    for (int i = 0; i < 7; ++i) {
        if (22380544ull + (size_t)cands[i] * ((size_t)N_ * E_ * 4) <= ws_size) {
            c2 = cands[i];
            break;
        }
    }

    k_cvt<<<dim3(1536), dim3(256), 0, stream>>>(x, xb, (N_ * 512) / 4);
    k_cvt<<<dim3(256), dim3(256), 0, stream>>>(WQ, wqb, (512 * 512) / 4);
    k_cvt<<<dim3(256), dim3(256), 0, stream>>>(WK, wkb, (512 * 512) / 4);
    k_proj<<<dim3(48, 8, 2), dim3(256), 0, stream>>>(xb, wqb, wkb, Qb, Kb);
    k_transpose<<<dim3(48, 8), dim3(256), 0, stream>>>(Kb, Kt);
    k_repack_qk<<<dim3(768), dim3(256), 0, stream>>>(Kb, Kf);
    k_repack_pv<<<dim3(768), dim3(256), 0, stream>>>(Kt, Ktf);
    k_adjpack<<<dim3((N_ * N_) / 256), dim3(256), 0, stream>>>(adj, adjpT);
    k_pass1<<<dim3(96, 24), dim3(512), 0, stream>>>(Qb, Kf, adjpT, sep);
    k_finish<<<dim3(384), dim3(64), 0, stream>>>(Qb, sep, inv_se, energies);
    k_pass2<<<dim3(96, c2), dim3(512), 0, stream>>>(Qb, Kf, Ktf, inv_se, adjpT, amean,
                                                    pout, N_ / c2);
    k_reduce<<<dim3(1536), dim3(256), 0, stream>>>(pout, out, c2);
}

// Round 24
// 172.898 us; speedup vs baseline: 1.0102x; 1.0102x over previous
//
#include <hip/hip_runtime.h>

typedef unsigned short u16;
typedef unsigned char u8;
typedef unsigned int u32;
typedef unsigned long long u64;

using s16x8 = __attribute__((ext_vector_type(8))) short;
using u16x4 = __attribute__((ext_vector_type(4))) u16;
using u32x2 = __attribute__((ext_vector_type(2))) u32;
using u32x4 = __attribute__((ext_vector_type(4))) u32;
using f32x4 = __attribute__((ext_vector_type(4))) float;

constexpr int N_ = 3072;
constexpr int E_ = 512;
constexpr int H_ = 8;
// exp(0.125*s) = exp2(s * 0.125*log2(e))
#define EXPSC 0.1803368801111203f

__device__ __forceinline__ u16 f2bf(float f) {
    u32 u = __float_as_uint(f);
    u += 0x7fffu + ((u >> 16) & 1u);
    return (u16)(u >> 16);
}
__device__ __forceinline__ float b2f(u16 u) {
    return __uint_as_float(((u32)u) << 16);
}
__device__ __forceinline__ u32 cvt_pk_bf16(float lo, float hi) {
    u32 r;
    asm("v_cvt_pk_bf16_f32 %0, %1, %2" : "=v"(r) : "v"(lo), "v"(hi));
    return r;
}

// ---------- K0: f32 -> bf16 convert ----------
__global__ void k_cvt(const float* __restrict__ src, u16* __restrict__ dst, int n4) {
    int i = blockIdx.x * blockDim.x + threadIdx.x;
    if (i >= n4) return;
    float4 v = ((const float4*)src)[i];
    u16x4 o = { f2bf(v.x), f2bf(v.y), f2bf(v.z), f2bf(v.w) };
    ((u16x4*)dst)[i] = o;
}

// ---------- K0b: pack adj int32 -> TRANSPOSED bitmask u64: adjpT[mword][n] ----------
__global__ void k_adjpack(const int* __restrict__ adj, u64* __restrict__ adjpT) {
    int i = blockIdx.x * blockDim.x + threadIdx.x;
    int v = adj[i];
    u64 m = __ballot(v != 0);
    if ((threadIdx.x & 63) == 0) {
        int n = i / 3072;
        int mw = (i - n * 3072) >> 6;
        adjpT[mw * 3072 + n] = m;
    }
}

// ---------- K1: projection GEMM (proven) ----------
__global__ __launch_bounds__(256) void k_proj(
    const u16* __restrict__ xb, const u16* __restrict__ wqb,
    const u16* __restrict__ wkb, u16* __restrict__ Qb, u16* __restrict__ Kb)
{
    const int t = threadIdx.x, lane = t & 63, w = t >> 6;
    const int lr = lane & 15, lg = lane >> 4;
    const int n0 = blockIdx.x * 64 + w * 16;
    const int e0 = blockIdx.y * 64;
    const u16* wb = blockIdx.z ? wkb : wqb;
    u16* dst = blockIdx.z ? Kb : Qb;

    f32x4 acc[4];
#pragma unroll
    for (int cb = 0; cb < 4; ++cb) acc[cb] = f32x4{0.f, 0.f, 0.f, 0.f};

    for (int k0 = 0; k0 < 512; k0 += 32) {
        s16x8 a = *(const s16x8*)(xb + (n0 + lr) * 512 + k0 + lg * 8);
#pragma unroll
        for (int cb = 0; cb < 4; ++cb) {
            s16x8 b = *(const s16x8*)(wb + (e0 + cb * 16 + lr) * 512 + k0 + lg * 8);
            acc[cb] = __builtin_amdgcn_mfma_f32_16x16x32_bf16(a, b, acc[cb], 0, 0, 0);
        }
    }
#pragma unroll
    for (int cb = 0; cb < 4; ++cb)
#pragma unroll
        for (int r = 0; r < 4; ++r)
            dst[(n0 + lg * 4 + r) * 512 + e0 + cb * 16 + lr] = f2bf(acc[cb][r]);
}

// ---------- K2t: transpose Kb -> Kt[512][3072] (proven) ----------
__global__ __launch_bounds__(256) void k_transpose(const u16* __restrict__ Kb,
                                                   u16* __restrict__ Kt) {
    __shared__ u16 tile[64 * 68];
    const int t = threadIdx.x;
    const int n0 = blockIdx.x * 64, e0 = blockIdx.y * 64;
    const int tr = t >> 4, c4 = (t & 15) * 4;
#pragma unroll
    for (int p = 0; p < 4; ++p) {
        int row = p * 16 + tr;
        u16x4 v = *(const u16x4*)(Kb + (n0 + row) * 512 + e0 + c4);
        *(u16x4*)&tile[row * 68 + c4] = v;
    }
    __syncthreads();
#pragma unroll
    for (int p = 0; p < 4; ++p) {
        int er = p * 16 + tr;
        u16x4 v = { tile[(c4 + 0) * 68 + er], tile[(c4 + 1) * 68 + er],
                    tile[(c4 + 2) * 68 + er], tile[(c4 + 3) * 68 + er] };
        *(u16x4*)(Kt + (e0 + er) * 3072 + n0 + c4) = v;
    }
}

// ---------- K2f: repack Kb into QK B-fragment-major layout (proven r11) ----------
__global__ __launch_bounds__(256) void k_repack_qk(const u16* __restrict__ Kb,
                                                   u16* __restrict__ Kf) {
    const int gid = blockIdx.x * 256 + threadIdx.x;
    const int frag = gid >> 6, lane = gid & 63;
    const int lr = lane & 15, lg = lane >> 4;
    const int M16 = frag >> 4, h = (frag >> 1) & 7, ks = frag & 1;
    s16x8 v = *(const s16x8*)(Kb + (M16 * 16 + lr) * 512 + h * 64 + ks * 32 + lg * 8);
    *(s16x8*)(Kf + frag * 512 + lane * 8) = v;
}

// ---------- K2g: repack Kt into PV B-fragment-major layout (proven r11) ----------
__global__ __launch_bounds__(256) void k_repack_pv(const u16* __restrict__ Kt,
                                                   u16* __restrict__ Ktf) {
    const int gid = blockIdx.x * 256 + threadIdx.x;
    const int frag = gid >> 6, lane = gid & 63;
    const int lr = lane & 15, lg = lane >> 4;
    const int h = frag / 384;
    const int rem = frag - h * 384;
    const int db = rem / 96, M32 = rem - db * 96;
    s16x8 v = *(const s16x8*)(Kt + (h * 64 + db * 16 + lr) * 3072 + M32 * 32 + lg * 8);
    *(s16x8*)(Ktf + frag * 512 + lane * 8) = v;
}

// ---------- K3: pass 1 — wave = head, n-tile 32 (2 ns); 16 m-chunks of 192.
__global__ __launch_bounds__(512, 4) void k_pass1(
    const u16* __restrict__ Qb, const u16* __restrict__ Kf,
    const u64* __restrict__ adjpT, float* __restrict__ sep)
{
    const int t = threadIdx.x, lane = t & 63, h = t >> 6;
    const int lr = lane & 15, lg = lane >> 4;
    const int n0 = blockIdx.x * 32;
    const int mbase = blockIdx.y * 192;

    s16x8 qa[2][2];   // [ns][ks]
#pragma unroll
    for (int ns = 0; ns < 2; ++ns)
#pragma unroll
        for (int ks = 0; ks < 2; ++ks)
            qa[ns][ks] = *(const s16x8*)(Qb + (n0 + ns * 16 + lr) * 512 +
                                         h * 64 + ks * 32 + lg * 8);
    float racc[2][4];
#pragma unroll
    for (int ns = 0; ns < 2; ++ns)
#pragma unroll
        for (int cb = 0; cb < 4; ++cb) racc[ns][cb] = 0.f;
    const f32x4 z = {0.f, 0.f, 0.f, 0.f};

    for (int ms = 0; ms < 3; ++ms) {
        const int m0 = mbase + ms * 64;
        const u64 aw0 = adjpT[(m0 >> 6) * 3072 + n0 + lr];
        const u64 aw1 = adjpT[(m0 >> 6) * 3072 + n0 + 16 + lr];
        s16x8 kf[4][2];
#pragma unroll
        for (int cb = 0; cb < 4; ++cb) {
            const u16* fb = Kf + (((m0 >> 4) + cb) * 16 + h * 2) * 512 + lane * 8;
            kf[cb][0] = *(const s16x8*)(fb);
            kf[cb][1] = *(const s16x8*)(fb + 512);
        }
#pragma unroll
        for (int cb = 0; cb < 4; ++cb) {
#pragma unroll
            for (int ns = 0; ns < 2; ++ns) {
                f32x4 s = __builtin_amdgcn_mfma_f32_16x16x32_bf16(kf[cb][0], qa[ns][0], z, 0, 0, 0);
                s = __builtin_amdgcn_mfma_f32_16x16x32_bf16(kf[cb][1], qa[ns][1], s, 0, 0, 0);
                const u64 aw = ns ? aw1 : aw0;
                const u32 nib = (u32)(aw >> (cb * 16 + lg * 4)) & 0xFu;
                float e0 = (nib & 1u) ? exp2f(EXPSC * s[0]) : 0.f;
                float e1 = (nib & 2u) ? exp2f(EXPSC * s[1]) : 0.f;
                float e2 = (nib & 4u) ? exp2f(EXPSC * s[2]) : 0.f;
                float e3 = (nib & 8u) ? exp2f(EXPSC * s[3]) : 0.f;
                racc[ns][cb] += (e0 + e1) + (e2 + e3);
            }
        }
    }
#pragma unroll
    for (int ns = 0; ns < 2; ++ns) {
        float v = (racc[ns][0] + racc[ns][1]) + (racc[ns][2] + racc[ns][3]);
        v += __shfl_xor(v, 16);
        v += __shfl_xor(v, 32);
        if (lane < 16)
            sep[(blockIdx.y * 8 + h) * N_ + n0 + ns * 16 + lr] = v;
    }
}

// ---------- K4: finish — inv_se + energies (16 partials) ----------
__global__ __launch_bounds__(64) void k_finish(
    const u16* __restrict__ Qb, const float* __restrict__ sep,
    float* __restrict__ inv_se, float* __restrict__ energies)
{
    const int lane = threadIdx.x;
    const int r = lane >> 3;
    const int h = lane & 7;
    const int n = blockIdx.x * 8 + r;

    float se = 0.f;
#pragma unroll
    for (int c = 0; c < 16; ++c) se += sep[(c * 8 + h) * N_ + n];

    float q2 = 0.f;
    const u16* qrow = Qb + n * 512 + h * 64;
#pragma unroll
    for (int j = 0; j < 8; ++j) {
        s16x8 v = *(const s16x8*)(qrow + j * 8);
#pragma unroll
        for (int e = 0; e < 8; ++e) {
            float f = b2f((u16)v[e]);
            q2 += f * f;
        }
    }

    inv_se[h * N_ + n] = 1.f / se;
    energies[h * N_ + n] = -8.0f * logf(se) + 0.5f * q2;
}

// ---------- K5: pass 2 — wave = head, n-tile 32 (2 ns); kt reused across ns;
// packed-bf16 P in LDS (stride 19) for amean head-sum. (EXACT r20/r22, proven)
__global__ __launch_bounds__(512, 4) void k_pass2(
    const u16* __restrict__ Qb, const u16* __restrict__ Kf,
    const u16* __restrict__ Ktf, const float* __restrict__ inv_se,
    const u64* __restrict__ adjpT, float* __restrict__ amean,
    float* __restrict__ pout, int mrange)
{
    __shared__ u32 plds[8 * 64 * 19];   // [head][lane][2ns x 4cb x 2 u32, pad->19]
    const int t = threadIdx.x, lane = t & 63, h = t >> 6;   // wave = head
    const int lr = lane & 15, lg = lane >> 4;
    const int n0 = blockIdx.x * 32;
    const int mbase = blockIdx.y * mrange;

    s16x8 qa[2][2];   // [ns][ks]
#pragma unroll
    for (int ns = 0; ns < 2; ++ns)
#pragma unroll
        for (int ks = 0; ks < 2; ++ks)
            qa[ns][ks] = *(const s16x8*)(Qb + (n0 + ns * 16 + lr) * 512 +
                                         h * 64 + ks * 32 + lg * 8);
    float invv[2];
#pragma unroll
    for (int ns = 0; ns < 2; ++ns)
        invv[ns] = inv_se[h * N_ + n0 + ns * 16 + lr];

    f32x4 oacc[2][4];   // [ns][db]
#pragma unroll
    for (int ns = 0; ns < 2; ++ns)
#pragma unroll
        for (int db = 0; db < 4; ++db) oacc[ns][db] = f32x4{0.f, 0.f, 0.f, 0.f};

    // PV A-frag shuffle sources (verified r8-r18): lane lr holds P[n=..+lr].
    const int srcA = lr | (((lg * 2) & 3) << 4);
    const int srcB = lr | (((lg * 2 + 1) & 3) << 4);
    const bool hi = lg >= 2;

    const f32x4 z = {0.f, 0.f, 0.f, 0.f};
    const int msteps = mrange >> 6;
    for (int ms = 0; ms < msteps; ++ms) {
        const int m0 = mbase + ms * 64;
        const u64 aw0 = adjpT[(m0 >> 6) * 3072 + n0 + lr];
        const u64 aw1 = adjpT[(m0 >> 6) * 3072 + n0 + 16 + lr];
        // batched kf: 8 fragments for this (step, head)
        s16x8 kf[4][2];
#pragma unroll
        for (int cb = 0; cb < 4; ++cb) {
            const u16* fb = Kf + (((m0 >> 4) + cb) * 16 + h * 2) * 512 + lane * 8;
            kf[cb][0] = *(const s16x8*)(fb);
            kf[cb][1] = *(const s16x8*)(fb + 512);
        }
        // QK for both ns; P packed to registers + LDS
        u32 pw[2][4][2];   // [ns][cb][pair]
#pragma unroll
        for (int cb = 0; cb < 4; ++cb) {
#pragma unroll
            for (int ns = 0; ns < 2; ++ns) {
                f32x4 s = __builtin_amdgcn_mfma_f32_16x16x32_bf16(kf[cb][0], qa[ns][0], z, 0, 0, 0);
                s = __builtin_amdgcn_mfma_f32_16x16x32_bf16(kf[cb][1], qa[ns][1], s, 0, 0, 0);
                const u64 aw = ns ? aw1 : aw0;
                const u32 nib = (u32)(aw >> (cb * 16 + lg * 4)) & 0xFu;
                float p0 = (nib & 1u) ? exp2f(EXPSC * s[0]) * invv[ns] : 0.f;
                float p1 = (nib & 2u) ? exp2f(EXPSC * s[1]) * invv[ns] : 0.f;
                float p2 = (nib & 4u) ? exp2f(EXPSC * s[2]) * invv[ns] : 0.f;
                float p3 = (nib & 8u) ? exp2f(EXPSC * s[3]) * invv[ns] : 0.f;
                pw[ns][cb][0] = cvt_pk_bf16(p0, p1);
                pw[ns][cb][1] = cvt_pk_bf16(p2, p3);
                u32x2 pv = { pw[ns][cb][0], pw[ns][cb][1] };
                *(u32x2*)&plds[(h * 64 + lane) * 19 + ns * 8 + cb * 2] = pv;
            }
        }
        // PV: kt batched per ks, REUSED for both ns
#pragma unroll
        for (int ks = 0; ks < 2; ++ks) {
            s16x8 kt4[4];
#pragma unroll
            for (int db = 0; db < 4; ++db)
                kt4[db] = *(const s16x8*)(Ktf + ((h * 4 + db) * 96 +
                                          (m0 >> 5) + ks) * 512 + lane * 8);
#pragma unroll
            for (int ns = 0; ns < 2; ++ns) {
                u32 a0 = pw[ns][2 * ks][0], a1 = pw[ns][2 * ks][1];
                u32 c0 = pw[ns][2 * ks + 1][0], c1 = pw[ns][2 * ks + 1][1];
                u32 y00 = (u32)__shfl((int)a0, srcA);
                u32 y01 = (u32)__shfl((int)a1, srcA);
                u32 y02 = (u32)__shfl((int)a0, srcB);
                u32 y03 = (u32)__shfl((int)a1, srcB);
                u32 y10 = (u32)__shfl((int)c0, srcA);
                u32 y11 = (u32)__shfl((int)c1, srcA);
                u32 y12 = (u32)__shfl((int)c0, srcB);
                u32 y13 = (u32)__shfl((int)c1, srcB);
                u32x4 pav = { hi ? y10 : y00, hi ? y11 : y01,
                              hi ? y12 : y02, hi ? y13 : y03 };
                s16x8 pa = *(s16x8*)&pav;
#pragma unroll
                for (int db = 0; db < 4; ++db)
                    oacc[ns][db] = __builtin_amdgcn_mfma_f32_16x16x32_bf16(
                        pa, kt4[db], oacc[ns][db], 0, 0, 0);
            }
        }
        __syncthreads();
        {   // attn_mean: thread -> (row nl = t>>4 in [0,32), m-quad q = t&15);
            // one f32x4 quad per thread: 512 = 32 rows x 16 quads.
            const int nl = t >> 4;
            const int q = t & 15;
            const int srcl = (q & 3) * 16 + (nl & 15);
            const int idx = (nl >> 4) * 8 + (q >> 2) * 2;
            f32x4 sm = {0.f, 0.f, 0.f, 0.f};
#pragma unroll
            for (int wv = 0; wv < 8; ++wv) {
                u32x2 v = *(const u32x2*)&plds[(wv * 64 + srcl) * 19 + idx];
                sm[0] += b2f((u16)(v.x & 0xffffu));
                sm[1] += b2f((u16)(v.x >> 16));
                sm[2] += b2f((u16)(v.y & 0xffffu));
                sm[3] += b2f((u16)(v.y >> 16));
            }
            f32x4 o;
#pragma unroll
            for (int j = 0; j < 4; ++j) o[j] = sm[j] * 0.125f;
            *(f32x4*)(amean + (size_t)(n0 + nl) * 3072 + m0 + q * 4) = o;
        }
        __syncthreads();
    }
    float* po = pout + (size_t)blockIdx.y * (N_ * E_);
#pragma unroll
    for (int ns = 0; ns < 2; ++ns)
#pragma unroll
        for (int db = 0; db < 4; ++db)
#pragma unroll
            for (int r = 0; r < 4; ++r)
                po[(n0 + ns * 16 + lg * 4 + r) * 512 +
                   h * 64 + db * 16 + lr] = oacc[ns][db][r];
}

// ---------- K6: reduce partial out ----------
__global__ void k_reduce(const float* __restrict__ pout, float* __restrict__ out, int c2) {
    int i = blockIdx.x * blockDim.x + threadIdx.x;
    if (i >= (N_ * E_) / 4) return;
    const f32x4* p4 = (const f32x4*)pout;
    f32x4 s = p4[i];
    for (int c = 1; c < c2; ++c) s += p4[c * ((N_ * E_) / 4) + i];
    ((f32x4*)out)[i] = s;
}

extern "C" void kernel_launch(void* const* d_in, const int* in_sizes, int n_in,
                              void* d_out, int out_size, void* d_ws, size_t ws_size,
                              hipStream_t stream) {
    const float* x  = (const float*)d_in[0];
    const int*  adj = (const int*)d_in[1];     // bool input arrives as int32
    const float* WQ = (const float*)d_in[2];
    const float* WK = (const float*)d_in[3];
    float* out      = (float*)d_out;
    float* amean    = out + (size_t)N_ * E_;
    float* energies = out + (size_t)N_ * E_ + (size_t)N_ * N_;

    char* ws = (char*)d_ws;
    u16* xb     = (u16*)(ws);                 // dead after k_proj
    u64* adjpT  = (u64*)(ws);                 // aliases xb, written after k_proj
    u16* wqb    = (u16*)(ws + 3145728);
    u16* wkb    = (u16*)(ws + 3670016);
    u16* Qb     = (u16*)(ws + 4194304);
    u16* Kb     = (u16*)(ws + 7340032);
    u16* Kt     = (u16*)(ws + 10485760);
    u16* Kf     = (u16*)(ws + 13631488);      // 3 MB QK fragments
    u16* Ktf    = (u16*)(ws + 16777216);      // 3 MB PV fragments
    float* sep  = (float*)(ws + 19922944);    // 16 chunks x 8 heads x 3072 = 1.57 MB
    float* inv_se = (float*)(ws + 21495808);  // 96 KB
    float* pout = (float*)(ws + 21594112);

    int c2 = 1;
    const int cands[7] = {12, 8, 6, 4, 3, 2, 1};
    for (int i = 0; i < 7; ++i) {
        if (21594112ull + (size_t)cands[i] * ((size_t)N_ * E_ * 4) <= ws_size) {
            c2 = cands[i];
            break;
        }
    }

    k_cvt<<<dim3(1536), dim3(256), 0, stream>>>(x, xb, (N_ * 512) / 4);
    k_cvt<<<dim3(256), dim3(256), 0, stream>>>(WQ, wqb, (512 * 512) / 4);
    k_cvt<<<dim3(256), dim3(256), 0, stream>>>(WK, wkb, (512 * 512) / 4);
    k_proj<<<dim3(48, 8, 2), dim3(256), 0, stream>>>(xb, wqb, wkb, Qb, Kb);
    k_transpose<<<dim3(48, 8), dim3(256), 0, stream>>>(Kb, Kt);
    k_repack_qk<<<dim3(768), dim3(256), 0, stream>>>(Kb, Kf);
    k_repack_pv<<<dim3(768), dim3(256), 0, stream>>>(Kt, Ktf);
    k_adjpack<<<dim3((N_ * N_) / 256), dim3(256), 0, stream>>>(adj, adjpT);
    k_pass1<<<dim3(96, 16), dim3(512), 0, stream>>>(Qb, Kf, adjpT, sep);
    k_finish<<<dim3(384), dim3(64), 0, stream>>>(Qb, sep, inv_se, energies);
    k_pass2<<<dim3(96, c2), dim3(512), 0, stream>>>(Qb, Kf, Ktf, inv_se, adjpT, amean,
                                                    pout, N_ / c2);
    k_reduce<<<dim3(1536), dim3(256), 0, stream>>>(pout, out, c2);
}

// Round 25
// 171.066 us; speedup vs baseline: 1.0210x; 1.0107x over previous
//
#include <hip/hip_runtime.h>

typedef unsigned short u16;
typedef unsigned char u8;
typedef unsigned int u32;
typedef unsigned long long u64;

using s16x8 = __attribute__((ext_vector_type(8))) short;
using u16x4 = __attribute__((ext_vector_type(4))) u16;
using u32x2 = __attribute__((ext_vector_type(2))) u32;
using u32x4 = __attribute__((ext_vector_type(4))) u32;
using f32x4 = __attribute__((ext_vector_type(4))) float;

constexpr int N_ = 3072;
constexpr int E_ = 512;
constexpr int H_ = 8;
// exp(0.125*s) = exp2(s * 0.125*log2(e))
#define EXPSC 0.1803368801111203f
#define LN2 0.6931471805599453f

__device__ __forceinline__ u16 f2bf(float f) {
    u32 u = __float_as_uint(f);
    u += 0x7fffu + ((u >> 16) & 1u);
    return (u16)(u >> 16);
}
__device__ __forceinline__ float b2f(u16 u) {
    return __uint_as_float(((u32)u) << 16);
}
__device__ __forceinline__ u32 cvt_pk_bf16(float lo, float hi) {
    u32 r;
    asm("v_cvt_pk_bf16_f32 %0, %1, %2" : "=v"(r) : "v"(lo), "v"(hi));
    return r;
}

// ---------- K0: f32 -> bf16 convert ----------
__global__ void k_cvt(const float* __restrict__ src, u16* __restrict__ dst, int n4) {
    int i = blockIdx.x * blockDim.x + threadIdx.x;
    if (i >= n4) return;
    float4 v = ((const float4*)src)[i];
    u16x4 o = { f2bf(v.x), f2bf(v.y), f2bf(v.z), f2bf(v.w) };
    ((u16x4*)dst)[i] = o;
}

// ---------- K0b: pack adj int32 -> TRANSPOSED bitmask u64: adjpT[mword][n] ----------
__global__ void k_adjpack(const int* __restrict__ adj, u64* __restrict__ adjpT) {
    int i = blockIdx.x * blockDim.x + threadIdx.x;
    int v = adj[i];
    u64 m = __ballot(v != 0);
    if ((threadIdx.x & 63) == 0) {
        int n = i / 3072;
        int mw = (i - n * 3072) >> 6;
        adjpT[mw * 3072 + n] = m;
    }
}

// ---------- K1: projection GEMM (proven) ----------
__global__ __launch_bounds__(256) void k_proj(
    const u16* __restrict__ xb, const u16* __restrict__ wqb,
    const u16* __restrict__ wkb, u16* __restrict__ Qb, u16* __restrict__ Kb)
{
    const int t = threadIdx.x, lane = t & 63, w = t >> 6;
    const int lr = lane & 15, lg = lane >> 4;
    const int n0 = blockIdx.x * 64 + w * 16;
    const int e0 = blockIdx.y * 64;
    const u16* wb = blockIdx.z ? wkb : wqb;
    u16* dst = blockIdx.z ? Kb : Qb;

    f32x4 acc[4];
#pragma unroll
    for (int cb = 0; cb < 4; ++cb) acc[cb] = f32x4{0.f, 0.f, 0.f, 0.f};

    for (int k0 = 0; k0 < 512; k0 += 32) {
        s16x8 a = *(const s16x8*)(xb + (n0 + lr) * 512 + k0 + lg * 8);
#pragma unroll
        for (int cb = 0; cb < 4; ++cb) {
            s16x8 b = *(const s16x8*)(wb + (e0 + cb * 16 + lr) * 512 + k0 + lg * 8);
            acc[cb] = __builtin_amdgcn_mfma_f32_16x16x32_bf16(a, b, acc[cb], 0, 0, 0);
        }
    }
#pragma unroll
    for (int cb = 0; cb < 4; ++cb)
#pragma unroll
        for (int r = 0; r < 4; ++r)
            dst[(n0 + lg * 4 + r) * 512 + e0 + cb * 16 + lr] = f2bf(acc[cb][r]);
}

// ---------- K2t: transpose Kb -> Kt[512][3072] (proven) ----------
__global__ __launch_bounds__(256) void k_transpose(const u16* __restrict__ Kb,
                                                   u16* __restrict__ Kt) {
    __shared__ u16 tile[64 * 68];
    const int t = threadIdx.x;
    const int n0 = blockIdx.x * 64, e0 = blockIdx.y * 64;
    const int tr = t >> 4, c4 = (t & 15) * 4;
#pragma unroll
    for (int p = 0; p < 4; ++p) {
        int row = p * 16 + tr;
        u16x4 v = *(const u16x4*)(Kb + (n0 + row) * 512 + e0 + c4);
        *(u16x4*)&tile[row * 68 + c4] = v;
    }
    __syncthreads();
#pragma unroll
    for (int p = 0; p < 4; ++p) {
        int er = p * 16 + tr;
        u16x4 v = { tile[(c4 + 0) * 68 + er], tile[(c4 + 1) * 68 + er],
                    tile[(c4 + 2) * 68 + er], tile[(c4 + 3) * 68 + er] };
        *(u16x4*)(Kt + (e0 + er) * 3072 + n0 + c4) = v;
    }
}

// ---------- K2f: repack Kb into QK B-fragment-major layout (proven r11) ----------
__global__ __launch_bounds__(256) void k_repack_qk(const u16* __restrict__ Kb,
                                                   u16* __restrict__ Kf) {
    const int gid = blockIdx.x * 256 + threadIdx.x;
    const int frag = gid >> 6, lane = gid & 63;
    const int lr = lane & 15, lg = lane >> 4;
    const int M16 = frag >> 4, h = (frag >> 1) & 7, ks = frag & 1;
    s16x8 v = *(const s16x8*)(Kb + (M16 * 16 + lr) * 512 + h * 64 + ks * 32 + lg * 8);
    *(s16x8*)(Kf + frag * 512 + lane * 8) = v;
}

// ---------- K2g: repack Kt into PV B-fragment-major layout (proven r11) ----------
__global__ __launch_bounds__(256) void k_repack_pv(const u16* __restrict__ Kt,
                                                   u16* __restrict__ Ktf) {
    const int gid = blockIdx.x * 256 + threadIdx.x;
    const int frag = gid >> 6, lane = gid & 63;
    const int lr = lane & 15, lg = lane >> 4;
    const int h = frag / 384;
    const int rem = frag - h * 384;
    const int db = rem / 96, M32 = rem - db * 96;
    s16x8 v = *(const s16x8*)(Kt + (h * 64 + db * 16 + lr) * 3072 + M32 * 32 + lg * 8);
    *(s16x8*)(Ktf + frag * 512 + lane * 8) = v;
}

// ---------- K3: pass 1 — wave = head, n-tile 32 (2 ns); 16 m-chunks of 192.
__global__ __launch_bounds__(512, 4) void k_pass1(
    const u16* __restrict__ Qb, const u16* __restrict__ Kf,
    const u64* __restrict__ adjpT, float* __restrict__ sep)
{
    const int t = threadIdx.x, lane = t & 63, h = t >> 6;
    const int lr = lane & 15, lg = lane >> 4;
    const int n0 = blockIdx.x * 32;
    const int mbase = blockIdx.y * 192;

    s16x8 qa[2][2];   // [ns][ks]
#pragma unroll
    for (int ns = 0; ns < 2; ++ns)
#pragma unroll
        for (int ks = 0; ks < 2; ++ks)
            qa[ns][ks] = *(const s16x8*)(Qb + (n0 + ns * 16 + lr) * 512 +
                                         h * 64 + ks * 32 + lg * 8);
    float racc[2][4];
#pragma unroll
    for (int ns = 0; ns < 2; ++ns)
#pragma unroll
        for (int cb = 0; cb < 4; ++cb) racc[ns][cb] = 0.f;
    const f32x4 z = {0.f, 0.f, 0.f, 0.f};

    for (int ms = 0; ms < 3; ++ms) {
        const int m0 = mbase + ms * 64;
        const u64 aw0 = adjpT[(m0 >> 6) * 3072 + n0 + lr];
        const u64 aw1 = adjpT[(m0 >> 6) * 3072 + n0 + 16 + lr];
        s16x8 kf[4][2];
#pragma unroll
        for (int cb = 0; cb < 4; ++cb) {
            const u16* fb = Kf + (((m0 >> 4) + cb) * 16 + h * 2) * 512 + lane * 8;
            kf[cb][0] = *(const s16x8*)(fb);
            kf[cb][1] = *(const s16x8*)(fb + 512);
        }
#pragma unroll
        for (int cb = 0; cb < 4; ++cb) {
#pragma unroll
            for (int ns = 0; ns < 2; ++ns) {
                f32x4 s = __builtin_amdgcn_mfma_f32_16x16x32_bf16(kf[cb][0], qa[ns][0], z, 0, 0, 0);
                s = __builtin_amdgcn_mfma_f32_16x16x32_bf16(kf[cb][1], qa[ns][1], s, 0, 0, 0);
                const u64 aw = ns ? aw1 : aw0;
                const u32 nib = (u32)(aw >> (cb * 16 + lg * 4)) & 0xFu;
                float e0 = (nib & 1u) ? exp2f(EXPSC * s[0]) : 0.f;
                float e1 = (nib & 2u) ? exp2f(EXPSC * s[1]) : 0.f;
                float e2 = (nib & 4u) ? exp2f(EXPSC * s[2]) : 0.f;
                float e3 = (nib & 8u) ? exp2f(EXPSC * s[3]) : 0.f;
                racc[ns][cb] += (e0 + e1) + (e2 + e3);
            }
        }
    }
#pragma unroll
    for (int ns = 0; ns < 2; ++ns) {
        float v = (racc[ns][0] + racc[ns][1]) + (racc[ns][2] + racc[ns][3]);
        v += __shfl_xor(v, 16);
        v += __shfl_xor(v, 32);
        if (lane < 16)
            sep[(blockIdx.y * 8 + h) * N_ + n0 + ns * 16 + lr] = v;
    }
}

// ---------- K4: finish — lb = -log2(se) + energies (16 partials) ----------
__global__ __launch_bounds__(64) void k_finish(
    const u16* __restrict__ Qb, const float* __restrict__ sep,
    float* __restrict__ lbuf, float* __restrict__ energies)
{
    const int lane = threadIdx.x;
    const int r = lane >> 3;
    const int h = lane & 7;
    const int n = blockIdx.x * 8 + r;

    float se = 0.f;
#pragma unroll
    for (int c = 0; c < 16; ++c) se += sep[(c * 8 + h) * N_ + n];

    float q2 = 0.f;
    const u16* qrow = Qb + n * 512 + h * 64;
#pragma unroll
    for (int j = 0; j < 8; ++j) {
        s16x8 v = *(const s16x8*)(qrow + j * 8);
#pragma unroll
        for (int e = 0; e < 8; ++e) {
            float f = b2f((u16)v[e]);
            q2 += f * f;
        }
    }

    const float l2 = __log2f(se);
    lbuf[h * N_ + n] = -l2;                        // log2(1/se), folded into exp2
    energies[h * N_ + n] = -8.0f * (LN2 * l2) + 0.5f * q2;
}

// ---------- K5: pass 2 — wave = head, n-tile 32 (2 ns); kt reused across ns;
// normalization folded into the exponent: p = exp2(EXPSC*s + lb).
__global__ __launch_bounds__(512, 4) void k_pass2(
    const u16* __restrict__ Qb, const u16* __restrict__ Kf,
    const u16* __restrict__ Ktf, const float* __restrict__ lbuf,
    const u64* __restrict__ adjpT, float* __restrict__ amean,
    float* __restrict__ pout, int mrange)
{
    __shared__ u32 plds[8 * 64 * 19];   // [head][lane][2ns x 4cb x 2 u32, pad->19]
    const int t = threadIdx.x, lane = t & 63, h = t >> 6;   // wave = head
    const int lr = lane & 15, lg = lane >> 4;
    const int n0 = blockIdx.x * 32;
    const int mbase = blockIdx.y * mrange;

    s16x8 qa[2][2];   // [ns][ks]
#pragma unroll
    for (int ns = 0; ns < 2; ++ns)
#pragma unroll
        for (int ks = 0; ks < 2; ++ks)
            qa[ns][ks] = *(const s16x8*)(Qb + (n0 + ns * 16 + lr) * 512 +
                                         h * 64 + ks * 32 + lg * 8);
    float lb[2];
#pragma unroll
    for (int ns = 0; ns < 2; ++ns)
        lb[ns] = lbuf[h * N_ + n0 + ns * 16 + lr];

    f32x4 oacc[2][4];   // [ns][db]
#pragma unroll
    for (int ns = 0; ns < 2; ++ns)
#pragma unroll
        for (int db = 0; db < 4; ++db) oacc[ns][db] = f32x4{0.f, 0.f, 0.f, 0.f};

    // PV A-frag shuffle sources (verified r8-r18): lane lr holds P[n=..+lr].
    const int srcA = lr | (((lg * 2) & 3) << 4);
    const int srcB = lr | (((lg * 2 + 1) & 3) << 4);
    const bool hi = lg >= 2;

    const f32x4 z = {0.f, 0.f, 0.f, 0.f};
    const int msteps = mrange >> 6;
    for (int ms = 0; ms < msteps; ++ms) {
        const int m0 = mbase + ms * 64;
        const u64 aw0 = adjpT[(m0 >> 6) * 3072 + n0 + lr];
        const u64 aw1 = adjpT[(m0 >> 6) * 3072 + n0 + 16 + lr];
        // batched kf: 8 fragments for this (step, head)
        s16x8 kf[4][2];
#pragma unroll
        for (int cb = 0; cb < 4; ++cb) {
            const u16* fb = Kf + (((m0 >> 4) + cb) * 16 + h * 2) * 512 + lane * 8;
            kf[cb][0] = *(const s16x8*)(fb);
            kf[cb][1] = *(const s16x8*)(fb + 512);
        }
        // QK for both ns; P packed to registers + LDS
        u32 pw[2][4][2];   // [ns][cb][pair]
#pragma unroll
        for (int cb = 0; cb < 4; ++cb) {
#pragma unroll
            for (int ns = 0; ns < 2; ++ns) {
                f32x4 s = __builtin_amdgcn_mfma_f32_16x16x32_bf16(kf[cb][0], qa[ns][0], z, 0, 0, 0);
                s = __builtin_amdgcn_mfma_f32_16x16x32_bf16(kf[cb][1], qa[ns][1], s, 0, 0, 0);
                const u64 aw = ns ? aw1 : aw0;
                const u32 nib = (u32)(aw >> (cb * 16 + lg * 4)) & 0xFu;
                float p0 = (nib & 1u) ? exp2f(fmaf(EXPSC, s[0], lb[ns])) : 0.f;
                float p1 = (nib & 2u) ? exp2f(fmaf(EXPSC, s[1], lb[ns])) : 0.f;
                float p2 = (nib & 4u) ? exp2f(fmaf(EXPSC, s[2], lb[ns])) : 0.f;
                float p3 = (nib & 8u) ? exp2f(fmaf(EXPSC, s[3], lb[ns])) : 0.f;
                pw[ns][cb][0] = cvt_pk_bf16(p0, p1);
                pw[ns][cb][1] = cvt_pk_bf16(p2, p3);
                u32x2 pv = { pw[ns][cb][0], pw[ns][cb][1] };
                *(u32x2*)&plds[(h * 64 + lane) * 19 + ns * 8 + cb * 2] = pv;
            }
        }
        // PV: kt batched per ks, REUSED for both ns
#pragma unroll
        for (int ks = 0; ks < 2; ++ks) {
            s16x8 kt4[4];
#pragma unroll
            for (int db = 0; db < 4; ++db)
                kt4[db] = *(const s16x8*)(Ktf + ((h * 4 + db) * 96 +
                                          (m0 >> 5) + ks) * 512 + lane * 8);
#pragma unroll
            for (int ns = 0; ns < 2; ++ns) {
                u32 a0 = pw[ns][2 * ks][0], a1 = pw[ns][2 * ks][1];
                u32 c0 = pw[ns][2 * ks + 1][0], c1 = pw[ns][2 * ks + 1][1];
                u32 y00 = (u32)__shfl((int)a0, srcA);
                u32 y01 = (u32)__shfl((int)a1, srcA);
                u32 y02 = (u32)__shfl((int)a0, srcB);
                u32 y03 = (u32)__shfl((int)a1, srcB);
                u32 y10 = (u32)__shfl((int)c0, srcA);
                u32 y11 = (u32)__shfl((int)c1, srcA);
                u32 y12 = (u32)__shfl((int)c0, srcB);
                u32 y13 = (u32)__shfl((int)c1, srcB);
                u32x4 pav = { hi ? y10 : y00, hi ? y11 : y01,
                              hi ? y12 : y02, hi ? y13 : y03 };
                s16x8 pa = *(s16x8*)&pav;
#pragma unroll
                for (int db = 0; db < 4; ++db)
                    oacc[ns][db] = __builtin_amdgcn_mfma_f32_16x16x32_bf16(
                        pa, kt4[db], oacc[ns][db], 0, 0, 0);
            }
        }
        __syncthreads();
        {   // attn_mean: thread -> (row nl = t>>4 in [0,32), m-quad q = t&15);
            // one f32x4 quad per thread: 512 = 32 rows x 16 quads.
            const int nl = t >> 4;
            const int q = t & 15;
            const int srcl = (q & 3) * 16 + (nl & 15);
            const int idx = (nl >> 4) * 8 + (q >> 2) * 2;
            f32x4 sm = {0.f, 0.f, 0.f, 0.f};
#pragma unroll
            for (int wv = 0; wv < 8; ++wv) {
                u32x2 v = *(const u32x2*)&plds[(wv * 64 + srcl) * 19 + idx];
                sm[0] += b2f((u16)(v.x & 0xffffu));
                sm[1] += b2f((u16)(v.x >> 16));
                sm[2] += b2f((u16)(v.y & 0xffffu));
                sm[3] += b2f((u16)(v.y >> 16));
            }
            f32x4 o;
#pragma unroll
            for (int j = 0; j < 4; ++j) o[j] = sm[j] * 0.125f;
            *(f32x4*)(amean + (size_t)(n0 + nl) * 3072 + m0 + q * 4) = o;
        }
        __syncthreads();
    }
    float* po = pout + (size_t)blockIdx.y * (N_ * E_);
#pragma unroll
    for (int ns = 0; ns < 2; ++ns)
#pragma unroll
        for (int db = 0; db < 4; ++db)
#pragma unroll
            for (int r = 0; r < 4; ++r)
                po[(n0 + ns * 16 + lg * 4 + r) * 512 +
                   h * 64 + db * 16 + lr] = oacc[ns][db][r];
}

// ---------- K6: reduce partial out ----------
__global__ void k_reduce(const float* __restrict__ pout, float* __restrict__ out, int c2) {
    int i = blockIdx.x * blockDim.x + threadIdx.x;
    if (i >= (N_ * E_) / 4) return;
    const f32x4* p4 = (const f32x4*)pout;
    f32x4 s = p4[i];
    for (int c = 1; c < c2; ++c) s += p4[c * ((N_ * E_) / 4) + i];
    ((f32x4*)out)[i] = s;
}

extern "C" void kernel_launch(void* const* d_in, const int* in_sizes, int n_in,
                              void* d_out, int out_size, void* d_ws, size_t ws_size,
                              hipStream_t stream) {
    const float* x  = (const float*)d_in[0];
    const int*  adj = (const int*)d_in[1];     // bool input arrives as int32
    const float* WQ = (const float*)d_in[2];
    const float* WK = (const float*)d_in[3];
    float* out      = (float*)d_out;
    float* amean    = out + (size_t)N_ * E_;
    float* energies = out + (size_t)N_ * E_ + (size_t)N_ * N_;

    char* ws = (char*)d_ws;
    u16* xb     = (u16*)(ws);                 // dead after k_proj
    u64* adjpT  = (u64*)(ws);                 // aliases xb, written after k_proj
    u16* wqb    = (u16*)(ws + 3145728);
    u16* wkb    = (u16*)(ws + 3670016);
    u16* Qb     = (u16*)(ws + 4194304);
    u16* Kb     = (u16*)(ws + 7340032);
    u16* Kt     = (u16*)(ws + 10485760);
    u16* Kf     = (u16*)(ws + 13631488);      // 3 MB QK fragments
    u16* Ktf    = (u16*)(ws + 16777216);      // 3 MB PV fragments
    float* sep  = (float*)(ws + 19922944);    // 16 chunks x 8 heads x 3072 = 1.57 MB
    float* lbuf = (float*)(ws + 21495808);    // 96 KB: -log2(se)
    float* pout = (float*)(ws + 21594112);

    int c2 = 1;
    const int cands[7] = {12, 8, 6, 4, 3, 2, 1};
    for (int i = 0; i < 7; ++i) {
        if (21594112ull + (size_t)cands[i] * ((size_t)N_ * E_ * 4) <= ws_size) {
            c2 = cands[i];
            break;
        }
    }

    k_cvt<<<dim3(1536), dim3(256), 0, stream>>>(x, xb, (N_ * 512) / 4);
    k_cvt<<<dim3(256), dim3(256), 0, stream>>>(WQ, wqb, (512 * 512) / 4);
    k_cvt<<<dim3(256), dim3(256), 0, stream>>>(WK, wkb, (512 * 512) / 4);
    k_proj<<<dim3(48, 8, 2), dim3(256), 0, stream>>>(xb, wqb, wkb, Qb, Kb);
    k_transpose<<<dim3(48, 8), dim3(256), 0, stream>>>(Kb, Kt);
    k_repack_qk<<<dim3(768), dim3(256), 0, stream>>>(Kb, Kf);
    k_repack_pv<<<dim3(768), dim3(256), 0, stream>>>(Kt, Ktf);
    k_adjpack<<<dim3((N_ * N_) / 256), dim3(256), 0, stream>>>(adj, adjpT);
    k_pass1<<<dim3(96, 16), dim3(512), 0, stream>>>(Qb, Kf, adjpT, sep);
    k_finish<<<dim3(384), dim3(64), 0, stream>>>(Qb, sep, lbuf, energies);
    k_pass2<<<dim3(96, c2), dim3(512), 0, stream>>>(Qb, Kf, Ktf, lbuf, adjpT, amean,
                                                    pout, N_ / c2);
    k_reduce<<<dim3(1536), dim3(256), 0, stream>>>(pout, out, c2);
}

// Round 26
// 162.716 us; speedup vs baseline: 1.0734x; 1.0513x over previous
//
#include <hip/hip_runtime.h>

typedef unsigned short u16;
typedef unsigned char u8;
typedef unsigned int u32;
typedef unsigned long long u64;

using s16x8 = __attribute__((ext_vector_type(8))) short;
using u16x4 = __attribute__((ext_vector_type(4))) u16;
using u32x2 = __attribute__((ext_vector_type(2))) u32;
using u32x4 = __attribute__((ext_vector_type(4))) u32;
using f32x4 = __attribute__((ext_vector_type(4))) float;

constexpr int N_ = 3072;
constexpr int E_ = 512;
constexpr int H_ = 8;
// exp(0.125*s) = exp2(s * 0.125*log2(e))
#define EXPSC 0.1803368801111203f
#define LN2 0.6931471805599453f

__device__ __forceinline__ u16 f2bf(float f) {
    u32 u = __float_as_uint(f);
    u += 0x7fffu + ((u >> 16) & 1u);
    return (u16)(u >> 16);
}
__device__ __forceinline__ float b2f(u16 u) {
    return __uint_as_float(((u32)u) << 16);
}
__device__ __forceinline__ u32 cvt_pk_bf16(float lo, float hi) {
    u32 r;
    asm("v_cvt_pk_bf16_f32 %0, %1, %2" : "=v"(r) : "v"(lo), "v"(hi));
    return r;
}

// ---------- K0: f32 -> bf16 convert ----------
__global__ void k_cvt(const float* __restrict__ src, u16* __restrict__ dst, int n4) {
    int i = blockIdx.x * blockDim.x + threadIdx.x;
    if (i >= n4) return;
    float4 v = ((const float4*)src)[i];
    u16x4 o = { f2bf(v.x), f2bf(v.y), f2bf(v.z), f2bf(v.w) };
    ((u16x4*)dst)[i] = o;
}

// ---------- K0b: pack adj int32 -> TRANSPOSED bitmask u64: adjpT[mword][n] ----------
__global__ void k_adjpack(const int* __restrict__ adj, u64* __restrict__ adjpT) {
    int i = blockIdx.x * blockDim.x + threadIdx.x;
    int v = adj[i];
    u64 m = __ballot(v != 0);
    if ((threadIdx.x & 63) == 0) {
        int n = i / 3072;
        int mw = (i - n * 3072) >> 6;
        adjpT[mw * 3072 + n] = m;
    }
}

// ---------- K1: projection GEMM (proven) ----------
__global__ __launch_bounds__(256) void k_proj(
    const u16* __restrict__ xb, const u16* __restrict__ wqb,
    const u16* __restrict__ wkb, u16* __restrict__ Qb, u16* __restrict__ Kb)
{
    const int t = threadIdx.x, lane = t & 63, w = t >> 6;
    const int lr = lane & 15, lg = lane >> 4;
    const int n0 = blockIdx.x * 64 + w * 16;
    const int e0 = blockIdx.y * 64;
    const u16* wb = blockIdx.z ? wkb : wqb;
    u16* dst = blockIdx.z ? Kb : Qb;

    f32x4 acc[4];
#pragma unroll
    for (int cb = 0; cb < 4; ++cb) acc[cb] = f32x4{0.f, 0.f, 0.f, 0.f};

    for (int k0 = 0; k0 < 512; k0 += 32) {
        s16x8 a = *(const s16x8*)(xb + (n0 + lr) * 512 + k0 + lg * 8);
#pragma unroll
        for (int cb = 0; cb < 4; ++cb) {
            s16x8 b = *(const s16x8*)(wb + (e0 + cb * 16 + lr) * 512 + k0 + lg * 8);
            acc[cb] = __builtin_amdgcn_mfma_f32_16x16x32_bf16(a, b, acc[cb], 0, 0, 0);
        }
    }
#pragma unroll
    for (int cb = 0; cb < 4; ++cb)
#pragma unroll
        for (int r = 0; r < 4; ++r)
            dst[(n0 + lg * 4 + r) * 512 + e0 + cb * 16 + lr] = f2bf(acc[cb][r]);
}

// ---------- K2t: transpose Kb -> Kt[512][3072] (proven) ----------
__global__ __launch_bounds__(256) void k_transpose(const u16* __restrict__ Kb,
                                                   u16* __restrict__ Kt) {
    __shared__ u16 tile[64 * 68];
    const int t = threadIdx.x;
    const int n0 = blockIdx.x * 64, e0 = blockIdx.y * 64;
    const int tr = t >> 4, c4 = (t & 15) * 4;
#pragma unroll
    for (int p = 0; p < 4; ++p) {
        int row = p * 16 + tr;
        u16x4 v = *(const u16x4*)(Kb + (n0 + row) * 512 + e0 + c4);
        *(u16x4*)&tile[row * 68 + c4] = v;
    }
    __syncthreads();
#pragma unroll
    for (int p = 0; p < 4; ++p) {
        int er = p * 16 + tr;
        u16x4 v = { tile[(c4 + 0) * 68 + er], tile[(c4 + 1) * 68 + er],
                    tile[(c4 + 2) * 68 + er], tile[(c4 + 3) * 68 + er] };
        *(u16x4*)(Kt + (e0 + er) * 3072 + n0 + c4) = v;
    }
}

// ---------- K2f: repack Kb into QK B-fragment-major layout (proven r11) ----------
__global__ __launch_bounds__(256) void k_repack_qk(const u16* __restrict__ Kb,
                                                   u16* __restrict__ Kf) {
    const int gid = blockIdx.x * 256 + threadIdx.x;
    const int frag = gid >> 6, lane = gid & 63;
    const int lr = lane & 15, lg = lane >> 4;
    const int M16 = frag >> 4, h = (frag >> 1) & 7, ks = frag & 1;
    s16x8 v = *(const s16x8*)(Kb + (M16 * 16 + lr) * 512 + h * 64 + ks * 32 + lg * 8);
    *(s16x8*)(Kf + frag * 512 + lane * 8) = v;
}

// ---------- K2g: repack Kt into PV B-fragment-major layout (proven r11) ----------
__global__ __launch_bounds__(256) void k_repack_pv(const u16* __restrict__ Kt,
                                                   u16* __restrict__ Ktf) {
    const int gid = blockIdx.x * 256 + threadIdx.x;
    const int frag = gid >> 6, lane = gid & 63;
    const int lr = lane & 15, lg = lane >> 4;
    const int h = frag / 384;
    const int rem = frag - h * 384;
    const int db = rem / 96, M32 = rem - db * 96;
    s16x8 v = *(const s16x8*)(Kt + (h * 64 + db * 16 + lr) * 3072 + M32 * 32 + lg * 8);
    *(s16x8*)(Ktf + frag * 512 + lane * 8) = v;
}

// ---------- K3: pass 1 — wave = head, n-tile 32 (2 ns); 16 m-chunks of 192.
__global__ __launch_bounds__(512, 4) void k_pass1(
    const u16* __restrict__ Qb, const u16* __restrict__ Kf,
    const u64* __restrict__ adjpT, float* __restrict__ sep)
{
    const int t = threadIdx.x, lane = t & 63, h = t >> 6;
    const int lr = lane & 15, lg = lane >> 4;
    const int n0 = blockIdx.x * 32;
    const int mbase = blockIdx.y * 192;

    s16x8 qa[2][2];   // [ns][ks]
#pragma unroll
    for (int ns = 0; ns < 2; ++ns)
#pragma unroll
        for (int ks = 0; ks < 2; ++ks)
            qa[ns][ks] = *(const s16x8*)(Qb + (n0 + ns * 16 + lr) * 512 +
                                         h * 64 + ks * 32 + lg * 8);
    float racc[2][4];
#pragma unroll
    for (int ns = 0; ns < 2; ++ns)
#pragma unroll
        for (int cb = 0; cb < 4; ++cb) racc[ns][cb] = 0.f;
    const f32x4 z = {0.f, 0.f, 0.f, 0.f};

    for (int ms = 0; ms < 3; ++ms) {
        const int m0 = mbase + ms * 64;
        const u64 aw0 = adjpT[(m0 >> 6) * 3072 + n0 + lr];
        const u64 aw1 = adjpT[(m0 >> 6) * 3072 + n0 + 16 + lr];
        s16x8 kf[4][2];
#pragma unroll
        for (int cb = 0; cb < 4; ++cb) {
            const u16* fb = Kf + (((m0 >> 4) + cb) * 16 + h * 2) * 512 + lane * 8;
            kf[cb][0] = *(const s16x8*)(fb);
            kf[cb][1] = *(const s16x8*)(fb + 512);
        }
#pragma unroll
        for (int cb = 0; cb < 4; ++cb) {
#pragma unroll
            for (int ns = 0; ns < 2; ++ns) {
                f32x4 s = __builtin_amdgcn_mfma_f32_16x16x32_bf16(kf[cb][0], qa[ns][0], z, 0, 0, 0);
                s = __builtin_amdgcn_mfma_f32_16x16x32_bf16(kf[cb][1], qa[ns][1], s, 0, 0, 0);
                const u64 aw = ns ? aw1 : aw0;
                const u32 nib = (u32)(aw >> (cb * 16 + lg * 4)) & 0xFu;
                float e0 = (nib & 1u) ? exp2f(EXPSC * s[0]) : 0.f;
                float e1 = (nib & 2u) ? exp2f(EXPSC * s[1]) : 0.f;
                float e2 = (nib & 4u) ? exp2f(EXPSC * s[2]) : 0.f;
                float e3 = (nib & 8u) ? exp2f(EXPSC * s[3]) : 0.f;
                racc[ns][cb] += (e0 + e1) + (e2 + e3);
            }
        }
    }
#pragma unroll
    for (int ns = 0; ns < 2; ++ns) {
        float v = (racc[ns][0] + racc[ns][1]) + (racc[ns][2] + racc[ns][3]);
        v += __shfl_xor(v, 16);
        v += __shfl_xor(v, 32);
        if (lane < 16)
            sep[(blockIdx.y * 8 + h) * N_ + n0 + ns * 16 + lr] = v;
    }
}

// ---------- K4: finish — lb = -log2(se) + energies (16 partials) ----------
__global__ __launch_bounds__(64) void k_finish(
    const u16* __restrict__ Qb, const float* __restrict__ sep,
    float* __restrict__ lbuf, float* __restrict__ energies)
{
    const int lane = threadIdx.x;
    const int r = lane >> 3;
    const int h = lane & 7;
    const int n = blockIdx.x * 8 + r;

    float se = 0.f;
#pragma unroll
    for (int c = 0; c < 16; ++c) se += sep[(c * 8 + h) * N_ + n];

    float q2 = 0.f;
    const u16* qrow = Qb + n * 512 + h * 64;
#pragma unroll
    for (int j = 0; j < 8; ++j) {
        s16x8 v = *(const s16x8*)(qrow + j * 8);
#pragma unroll
        for (int e = 0; e < 8; ++e) {
            float f = b2f((u16)v[e]);
            q2 += f * f;
        }
    }

    const float l2 = __log2f(se);
    lbuf[h * N_ + n] = -l2;                        // log2(1/se), folded into exp2
    energies[h * N_ + n] = -8.0f * (LN2 * l2) + 0.5f * q2;
}

// ---------- K5: pass 2 — wave = head, n-tile 32 (2 ns); kt reused across ns;
// normalization folded into the exponent: p = exp2(EXPSC*s + lb).
__global__ __launch_bounds__(512, 4) void k_pass2(
    const u16* __restrict__ Qb, const u16* __restrict__ Kf,
    const u16* __restrict__ Ktf, const float* __restrict__ lbuf,
    const u64* __restrict__ adjpT, float* __restrict__ amean,
    float* __restrict__ pout, int mrange)
{
    __shared__ u32 plds[8 * 64 * 19];   // [head][lane][2ns x 4cb x 2 u32, pad->19]
    const int t = threadIdx.x, lane = t & 63, h = t >> 6;   // wave = head
    const int lr = lane & 15, lg = lane >> 4;
    const int n0 = blockIdx.x * 32;
    const int mbase = blockIdx.y * mrange;

    s16x8 qa[2][2];   // [ns][ks]
#pragma unroll
    for (int ns = 0; ns < 2; ++ns)
#pragma unroll
        for (int ks = 0; ks < 2; ++ks)
            qa[ns][ks] = *(const s16x8*)(Qb + (n0 + ns * 16 + lr) * 512 +
                                         h * 64 + ks * 32 + lg * 8);
    float lb[2];
#pragma unroll
    for (int ns = 0; ns < 2; ++ns)
        lb[ns] = lbuf[h * N_ + n0 + ns * 16 + lr];

    f32x4 oacc[2][4];   // [ns][db]
#pragma unroll
    for (int ns = 0; ns < 2; ++ns)
#pragma unroll
        for (int db = 0; db < 4; ++db) oacc[ns][db] = f32x4{0.f, 0.f, 0.f, 0.f};

    // PV A-frag shuffle sources (verified r8-r18): lane lr holds P[n=..+lr].
    const int srcA = lr | (((lg * 2) & 3) << 4);
    const int srcB = lr | (((lg * 2 + 1) & 3) << 4);
    const bool hi = lg >= 2;

    const f32x4 z = {0.f, 0.f, 0.f, 0.f};
    const int msteps = mrange >> 6;
    for (int ms = 0; ms < msteps; ++ms) {
        const int m0 = mbase + ms * 64;
        const u64 aw0 = adjpT[(m0 >> 6) * 3072 + n0 + lr];
        const u64 aw1 = adjpT[(m0 >> 6) * 3072 + n0 + 16 + lr];
        // batched kf: 8 fragments for this (step, head)
        s16x8 kf[4][2];
#pragma unroll
        for (int cb = 0; cb < 4; ++cb) {
            const u16* fb = Kf + (((m0 >> 4) + cb) * 16 + h * 2) * 512 + lane * 8;
            kf[cb][0] = *(const s16x8*)(fb);
            kf[cb][1] = *(const s16x8*)(fb + 512);
        }
        // QK for both ns; P packed to registers + LDS
        u32 pw[2][4][2];   // [ns][cb][pair]
#pragma unroll
        for (int cb = 0; cb < 4; ++cb) {
#pragma unroll
            for (int ns = 0; ns < 2; ++ns) {
                f32x4 s = __builtin_amdgcn_mfma_f32_16x16x32_bf16(kf[cb][0], qa[ns][0], z, 0, 0, 0);
                s = __builtin_amdgcn_mfma_f32_16x16x32_bf16(kf[cb][1], qa[ns][1], s, 0, 0, 0);
                const u64 aw = ns ? aw1 : aw0;
                const u32 nib = (u32)(aw >> (cb * 16 + lg * 4)) & 0xFu;
                float p0 = (nib & 1u) ? exp2f(fmaf(EXPSC, s[0], lb[ns])) : 0.f;
                float p1 = (nib & 2u) ? exp2f(fmaf(EXPSC, s[1], lb[ns])) : 0.f;
                float p2 = (nib & 4u) ? exp2f(fmaf(EXPSC, s[2], lb[ns])) : 0.f;
                float p3 = (nib & 8u) ? exp2f(fmaf(EXPSC, s[3], lb[ns])) : 0.f;
                pw[ns][cb][0] = cvt_pk_bf16(p0, p1);
                pw[ns][cb][1] = cvt_pk_bf16(p2, p3);
                u32x2 pv = { pw[ns][cb][0], pw[ns][cb][1] };
                *(u32x2*)&plds[(h * 64 + lane) * 19 + ns * 8 + cb * 2] = pv;
            }
        }
        // PV: kt batched per ks, REUSED for both ns
#pragma unroll
        for (int ks = 0; ks < 2; ++ks) {
            s16x8 kt4[4];
#pragma unroll
            for (int db = 0; db < 4; ++db)
                kt4[db] = *(const s16x8*)(Ktf + ((h * 4 + db) * 96 +
                                          (m0 >> 5) + ks) * 512 + lane * 8);
#pragma unroll
            for (int ns = 0; ns < 2; ++ns) {
                u32 a0 = pw[ns][2 * ks][0], a1 = pw[ns][2 * ks][1];
                u32 c0 = pw[ns][2 * ks + 1][0], c1 = pw[ns][2 * ks + 1][1];
                u32 y00 = (u32)__shfl((int)a0, srcA);
                u32 y01 = (u32)__shfl((int)a1, srcA);
                u32 y02 = (u32)__shfl((int)a0, srcB);
                u32 y03 = (u32)__shfl((int)a1, srcB);
                u32 y10 = (u32)__shfl((int)c0, srcA);
                u32 y11 = (u32)__shfl((int)c1, srcA);
                u32 y12 = (u32)__shfl((int)c0, srcB);
                u32 y13 = (u32)__shfl((int)c1, srcB);
                u32x4 pav = { hi ? y10 : y00, hi ? y11 : y01,
                              hi ? y12 : y02, hi ? y13 : y03 };
                s16x8 pa = *(s16x8*)&pav;
#pragma unroll
                for (int db = 0; db < 4; ++db)
                    oacc[ns][db] = __builtin_amdgcn_mfma_f32_16x16x32_bf16(
                        pa, kt4[db], oacc[ns][db], 0, 0, 0);
            }
        }
        __syncthreads();
        {   // attn_mean: thread -> (row nl = t>>4 in [0,32), m-quad q = t&15);
            // one f32x4 quad per thread: 512 = 32 rows x 16 quads.
            const int nl = t >> 4;
            const int q = t & 15;
            const int srcl = (q & 3) * 16 + (nl & 15);
            const int idx = (nl >> 4) * 8 + (q >> 2) * 2;
            f32x4 sm = {0.f, 0.f, 0.f, 0.f};
#pragma unroll
            for (int wv = 0; wv < 8; ++wv) {
                u32x2 v = *(const u32x2*)&plds[(wv * 64 + srcl) * 19 + idx];
                sm[0] += b2f((u16)(v.x & 0xffffu));
                sm[1] += b2f((u16)(v.x >> 16));
                sm[2] += b2f((u16)(v.y & 0xffffu));
                sm[3] += b2f((u16)(v.y >> 16));
            }
            f32x4 o;
#pragma unroll
            for (int j = 0; j < 4; ++j) o[j] = sm[j] * 0.125f;
            *(f32x4*)(amean + (size_t)(n0 + nl) * 3072 + m0 + q * 4) = o;
        }
        __syncthreads();
    }
    float* po = pout + (size_t)blockIdx.y * (N_ * E_);
#pragma unroll
    for (int ns = 0; ns < 2; ++ns)
#pragma unroll
        for (int db = 0; db < 4; ++db)
#pragma unroll
            for (int r = 0; r < 4; ++r)
                po[(n0 + ns * 16 + lg * 4 + r) * 512 +
                   h * 64 + db * 16 + lr] = oacc[ns][db][r];
}

// ---------- K6: reduce partial out ----------
__global__ void k_reduce(const float* __restrict__ pout, float* __restrict__ out, int c2) {
    int i = blockIdx.x * blockDim.x + threadIdx.x;
    if (i >= (N_ * E_) / 4) return;
    const f32x4* p4 = (const f32x4*)pout;
    f32x4 s = p4[i];
    for (int c = 1; c < c2; ++c) s += p4[c * ((N_ * E_) / 4) + i];
    ((f32x4*)out)[i] = s;
}

extern "C" void kernel_launch(void* const* d_in, const int* in_sizes, int n_in,
                              void* d_out, int out_size, void* d_ws, size_t ws_size,
                              hipStream_t stream) {
    const float* x  = (const float*)d_in[0];
    const int*  adj = (const int*)d_in[1];     // bool input arrives as int32
    const float* WQ = (const float*)d_in[2];
    const float* WK = (const float*)d_in[3];
    float* out      = (float*)d_out;
    float* amean    = out + (size_t)N_ * E_;
    float* energies = out + (size_t)N_ * E_ + (size_t)N_ * N_;

    char* ws = (char*)d_ws;
    u16* xb     = (u16*)(ws);                 // dead after k_proj
    u64* adjpT  = (u64*)(ws);                 // aliases xb, written after k_proj
    u16* wqb    = (u16*)(ws + 3145728);
    u16* wkb    = (u16*)(ws + 3670016);
    u16* Qb     = (u16*)(ws + 4194304);
    u16* Kb     = (u16*)(ws + 7340032);
    u16* Kt     = (u16*)(ws + 10485760);
    u16* Kf     = (u16*)(ws + 13631488);      // 3 MB QK fragments
    u16* Ktf    = (u16*)(ws + 16777216);      // 3 MB PV fragments
    float* sep  = (float*)(ws + 19922944);    // 16 chunks x 8 heads x 3072 = 1.57 MB
    float* lbuf = (float*)(ws + 21495808);    // 96 KB: -log2(se)
    float* pout = (float*)(ws + 21594112);

    int c2 = 1;
    const int cands[6] = {8, 6, 4, 3, 2, 1};
    for (int i = 0; i < 6; ++i) {
        if (21594112ull + (size_t)cands[i] * ((size_t)N_ * E_ * 4) <= ws_size) {
            c2 = cands[i];
            break;
        }
    }

    k_cvt<<<dim3(1536), dim3(256), 0, stream>>>(x, xb, (N_ * 512) / 4);
    k_cvt<<<dim3(256), dim3(256), 0, stream>>>(WQ, wqb, (512 * 512) / 4);
    k_cvt<<<dim3(256), dim3(256), 0, stream>>>(WK, wkb, (512 * 512) / 4);
    k_proj<<<dim3(48, 8, 2), dim3(256), 0, stream>>>(xb, wqb, wkb, Qb, Kb);
    k_transpose<<<dim3(48, 8), dim3(256), 0, stream>>>(Kb, Kt);
    k_repack_qk<<<dim3(768), dim3(256), 0, stream>>>(Kb, Kf);
    k_repack_pv<<<dim3(768), dim3(256), 0, stream>>>(Kt, Ktf);
    k_adjpack<<<dim3((N_ * N_) / 256), dim3(256), 0, stream>>>(adj, adjpT);
    k_pass1<<<dim3(96, 16), dim3(512), 0, stream>>>(Qb, Kf, adjpT, sep);
    k_finish<<<dim3(384), dim3(64), 0, stream>>>(Qb, sep, lbuf, energies);
    k_pass2<<<dim3(96, c2), dim3(512), 0, stream>>>(Qb, Kf, Ktf, lbuf, adjpT, amean,
                                                    pout, N_ / c2);
    k_reduce<<<dim3(1536), dim3(256), 0, stream>>>(pout, out, c2);
}